// Round 1
// baseline (446.462 us; speedup 1.0000x reference)
//
#include <hip/hip_runtime.h>
#include <hip/hip_bf16.h>
#include <cstddef>

// Problem constants (B=8, S1=256, S2=64, VIDEO=1024, TEXT=768, ATTN=512, OUT=500)
#define MBP   2048   // B*S1
#define MT    512    // B*S2
#define ADIM  512
#define VDIM  1024
#define TDIM  768
#define NOUT  500
#define CDIM  2048   // 4*ADIM

__device__ __forceinline__ float tanh_fast(float x) {
    // tanh(x) = 1 - 2/(exp(2x)+1); handles +-inf saturation naturally.
    float e = __expf(2.0f * x);
    return 1.0f - 2.0f / (e + 1.0f);
}

// Generic fp32 GEMM: C[M,N] = A[M,K] @ B[K,N] (+ bias[N] if non-null).
// Requirements: M % 64 == 0, K % 32 == 0. N arbitrary (guarded).
// 64x64 tile, BK=32, 256 threads, 4x4 micro-tile.
__global__ __launch_bounds__(256) void gemm_f32(
    const float* __restrict__ A, const float* __restrict__ B,
    const float* __restrict__ bias, float* __restrict__ C,
    int M, int N, int K)
{
    __shared__ float As[32][68];  // [k][m], padded row to break store conflicts
    __shared__ float Bs[32][64];  // [k][n]

    const int t   = threadIdx.x;
    const int tx  = t & 15, ty = t >> 4;
    const int row0 = blockIdx.x * 64, col0 = blockIdx.y * 64;

    // A-load mapping: thread covers row (row0+am), k = ak..ak+3 and ak+16..ak+19
    const int am = t >> 2, ak = (t & 3) << 2;
    // B-load mapping: thread covers col (col0+bn), rows bk, bk+4, ..., bk+28
    const int bn = t & 63, bk = t >> 6;

    const float* Ap  = A + (size_t)(row0 + am) * K + ak;
    const int   bcol = col0 + bn;

    float acc[4][4] = {{0.f}};

    for (int k0 = 0; k0 < K; k0 += 32) {
        float4 a0 = *(const float4*)(Ap + k0);
        float4 a1 = *(const float4*)(Ap + k0 + 16);
        As[ak + 0][am] = a0.x; As[ak + 1][am] = a0.y;
        As[ak + 2][am] = a0.z; As[ak + 3][am] = a0.w;
        As[ak + 16][am] = a1.x; As[ak + 17][am] = a1.y;
        As[ak + 18][am] = a1.z; As[ak + 19][am] = a1.w;
        #pragma unroll
        for (int i = 0; i < 8; ++i) {
            int k = bk + (i << 2);
            Bs[k][bn] = (bcol < N) ? B[(size_t)(k0 + k) * N + bcol] : 0.0f;
        }
        __syncthreads();
        #pragma unroll
        for (int k = 0; k < 32; ++k) {
            float4 a = *(const float4*)&As[k][ty << 2];
            float4 b = *(const float4*)&Bs[k][tx << 2];
            acc[0][0] += a.x * b.x; acc[0][1] += a.x * b.y;
            acc[0][2] += a.x * b.z; acc[0][3] += a.x * b.w;
            acc[1][0] += a.y * b.x; acc[1][1] += a.y * b.y;
            acc[1][2] += a.y * b.z; acc[1][3] += a.y * b.w;
            acc[2][0] += a.z * b.x; acc[2][1] += a.z * b.y;
            acc[2][2] += a.z * b.z; acc[2][3] += a.z * b.w;
            acc[3][0] += a.w * b.x; acc[3][1] += a.w * b.y;
            acc[3][2] += a.w * b.z; acc[3][3] += a.w * b.w;
        }
        __syncthreads();
    }

    #pragma unroll
    for (int i = 0; i < 4; ++i) {
        int row = row0 + (ty << 2) + i;
        #pragma unroll
        for (int j = 0; j < 4; ++j) {
            int col = col0 + (tx << 2) + j;
            if (col < N) {
                float v = acc[i][j];
                if (bias) v += bias[col];
                C[(size_t)row * N + col] = v;
            }
        }
    }
}

// Fused per-(b,p): e[q] = sum_a tanh(h1[a]+h2[q][a]+bias[a])*w3[a];
// softmax over q; text_attn[a] = sum_q p[q]*h2[q][a];
// tcont row = tanh([h1, ta, h1*ta, h1-ta]).
// One block per (b,p); 256 threads = 4 waves; each wave handles 16 q's.
__global__ __launch_bounds__(256) void attn_fused(
    const float* __restrict__ h1,   // [2048][512]
    const float* __restrict__ h2,   // [8][64][512]
    const float* __restrict__ bias, // [512]
    const float* __restrict__ w3,   // [512]
    float* __restrict__ tcont)      // [2048][2048]
{
    __shared__ float h1s[ADIM];   // raw h1 row
    __shared__ float hbs[ADIM];   // h1 + bias (tanh pre-add)
    __shared__ float w3s[ADIM];
    __shared__ float sc[64];      // e then softmax scores

    const int bp = blockIdx.x;          // b*256 + p
    const int b  = bp >> 8;
    const int t  = threadIdx.x;
    const float* h1r = h1 + (size_t)bp * ADIM;
    const float* h2b = h2 + (size_t)b * 64 * ADIM;

    for (int i = t; i < ADIM; i += 256) {
        float v = h1r[i];
        h1s[i] = v;
        hbs[i] = v + bias[i];
        w3s[i] = w3[i];
    }
    __syncthreads();

    const int wave = t >> 6, lane = t & 63;
    #pragma unroll 4
    for (int qi = 0; qi < 16; ++qi) {
        int q = (wave << 4) + qi;
        const float* h2q = h2b + (q << 9);
        float s = 0.f;
        #pragma unroll
        for (int j = 0; j < 8; ++j) {
            int a = lane + (j << 6);
            s += tanh_fast(hbs[a] + h2q[a]) * w3s[a];
        }
        #pragma unroll
        for (int off = 32; off; off >>= 1) s += __shfl_down(s, off, 64);
        if (lane == 0) sc[q] = s;
    }
    __syncthreads();

    // softmax over the 64 logits, done by wave 0 (lane q)
    if (t < 64) {
        float e = sc[t];
        float m = e;
        #pragma unroll
        for (int off = 32; off; off >>= 1) m = fmaxf(m, __shfl_xor(m, off, 64));
        float ex = __expf(e - m);
        float s = ex;
        #pragma unroll
        for (int off = 32; off; off >>= 1) s += __shfl_xor(s, off, 64);
        sc[t] = ex / s;
    }
    __syncthreads();

    float* o = tcont + (size_t)bp * CDIM;
    for (int av = t; av < ADIM; av += 256) {
        float ta = 0.f;
        #pragma unroll 8
        for (int q = 0; q < 64; ++q) ta += sc[q] * h2b[(q << 9) + av];
        float hh = h1s[av];
        o[av]            = tanh_fast(hh);
        o[ADIM + av]     = tanh_fast(ta);
        o[2 * ADIM + av] = tanh_fast(hh * ta);
        o[3 * ADIM + av] = tanh_fast(hh - ta);
    }
}

extern "C" void kernel_launch(void* const* d_in, const int* in_sizes, int n_in,
                              void* d_out, int out_size, void* d_ws, size_t ws_size,
                              hipStream_t stream) {
    const float* video = (const float*)d_in[0];  // [8,256,1024]
    const float* text  = (const float*)d_in[1];  // [8,64,768]
    // d_in[2]/d_in[3] are masks — dead in the reference (masked_fill result discarded)
    const float* w1   = (const float*)d_in[4];   // [1024,512]
    const float* w2   = (const float*)d_in[5];   // [768,512]
    const float* w3   = (const float*)d_in[6];   // [512,1]
    const float* bias = (const float*)d_in[7];   // [512]
    const float* w4   = (const float*)d_in[8];   // [2048,500]
    const float* b4   = (const float*)d_in[9];   // [500]
    float* out = (float*)d_out;                  // [8,256,500]

    char* ws = (char*)d_ws;
    float* h1 = (float*)ws;                                  // 2048*512 = 4 MB
    float* h2 = (float*)(ws + (size_t)MBP * ADIM * 4);       // 512*512  = 1 MB
    float* tc = (float*)(ws + (size_t)(MBP * ADIM + MT * ADIM) * 4); // 2048*2048 = 16 MB

    // h1 = video @ w1    [2048,1024]x[1024,512]
    gemm_f32<<<dim3(MBP / 64, ADIM / 64), 256, 0, stream>>>(video, w1, nullptr, h1, MBP, ADIM, VDIM);
    // h2 = text @ w2     [512,768]x[768,512]
    gemm_f32<<<dim3(MT / 64, ADIM / 64), 256, 0, stream>>>(text, w2, nullptr, h2, MT, ADIM, TDIM);
    // fused additive attention + softmax + text_attn + cont features + tanh
    attn_fused<<<MBP, 256, 0, stream>>>(h1, h2, bias, w3, tc);
    // out = tanh(cont) @ w4 + b4   [2048,2048]x[2048,500]
    gemm_f32<<<dim3(MBP / 64, (NOUT + 63) / 64), 256, 0, stream>>>(tc, w4, b4, out, MBP, NOUT, CDIM);
}

// Round 3
// 207.820 us; speedup vs baseline: 2.1483x; 2.1483x over previous
//
#include <hip/hip_runtime.h>
#include <hip/hip_bf16.h>
#include <cstddef>

// Problem constants (B=8, S1=256, S2=64, VIDEO=1024, TEXT=768, ATTN=512, OUT=500)
#define MBP   2048   // B*S1
#define MT    512    // B*S2
#define ADIM  512
#define VDIM  1024
#define TDIM  768
#define NOUT  500
#define CDIM  2048   // 4*ADIM

typedef __attribute__((ext_vector_type(8))) short short8;    // 8 bf16 = 4 VGPRs
typedef __attribute__((ext_vector_type(4))) float floatx4;   // MFMA C/D frag

__device__ __forceinline__ float tanh_fast(float x) {
    float e = __expf(2.0f * x);
    return 1.0f - 2.0f / (e + 1.0f);
}

__device__ __forceinline__ unsigned short bf16r(float x) {
    union { float f; unsigned int u; } c; c.f = x;
    unsigned int r = (c.u + 0x7fffu + ((c.u >> 16) & 1u)) >> 16;
    return (unsigned short)r;
}
__device__ __forceinline__ float bf2f(unsigned short h) {
    union { unsigned int u; float f; } c; c.u = ((unsigned int)h) << 16;
    return c.f;
}

// fp32 -> (hi, lo) bf16 split: x ~= hi + lo with residual ~2^-18 relative.
__global__ __launch_bounds__(256) void conv_split(
    const float* __restrict__ src,
    unsigned short* __restrict__ hi, unsigned short* __restrict__ lo, int n4)
{
    int i = blockIdx.x * 256 + threadIdx.x;
    if (i < n4) {
        float4 v = ((const float4*)src)[i];
        ushort4 h, l;
        h.x = bf16r(v.x); l.x = bf16r(v.x - bf2f(h.x));
        h.y = bf16r(v.y); l.y = bf16r(v.y - bf2f(h.y));
        h.z = bf16r(v.z); l.z = bf16r(v.z - bf2f(h.z));
        h.w = bf16r(v.w); l.w = bf16r(v.w - bf2f(h.w));
        ((ushort4*)hi)[i] = h;
        ((ushort4*)lo)[i] = l;
    }
}

// src [R][C] fp32 -> transpose [C][R], split hi/lo bf16.
__global__ __launch_bounds__(256) void transp_split(
    const float* __restrict__ src,
    unsigned short* __restrict__ hi, unsigned short* __restrict__ lo, int R, int C)
{
    __shared__ float tile[32][33];
    const int tx = threadIdx.x & 31, ty = threadIdx.x >> 5;
    const int r0 = blockIdx.x * 32, c0 = blockIdx.y * 32;
    #pragma unroll
    for (int i = 0; i < 4; ++i) {
        int r = r0 + ty + i * 8, c = c0 + tx;
        if (r < R && c < C) tile[ty + i * 8][tx] = src[(size_t)r * C + c];
    }
    __syncthreads();
    #pragma unroll
    for (int i = 0; i < 4; ++i) {
        int c = c0 + ty + i * 8, r = r0 + tx;
        if (c < C && r < R) {
            float v = tile[tx][ty + i * 8];
            unsigned short h = bf16r(v);
            hi[(size_t)c * R + r] = h;
            lo[(size_t)c * R + r] = bf16r(v - bf2f(h));
        }
    }
}

// src [R][C] fp32 -> dst [C][R] bf16 (single precision split not needed).
__global__ __launch_bounds__(256) void transp_bf16(
    const float* __restrict__ src, unsigned short* __restrict__ dst, int R, int C)
{
    __shared__ float tile[32][33];
    const int tx = threadIdx.x & 31, ty = threadIdx.x >> 5;
    const int r0 = blockIdx.x * 32, c0 = blockIdx.y * 32;
    #pragma unroll
    for (int i = 0; i < 4; ++i) {
        int r = r0 + ty + i * 8, c = c0 + tx;
        if (r < R && c < C) tile[ty + i * 8][tx] = src[(size_t)r * C + c];
    }
    __syncthreads();
    #pragma unroll
    for (int i = 0; i < 4; ++i) {
        int c = c0 + ty + i * 8, r = r0 + tx;
        if (c < C && r < R) dst[(size_t)c * R + r] = bf16r(tile[tx][ty + i * 8]);
    }
}

#define LP 40   // LDS row pitch in ushorts (80 B: 16-B aligned, odd bank stride)

// Compensated bf16 MFMA GEMM: C = (Ah+Al)[M,K] @ (Bh+Bl)[N,K]^T, fp32-accurate.
// 3 MFMAs per fragment pair: Ah*Bh + Ah*Bl + Al*Bh (Al*Bl dropped, ~2^-18).
// 64x64 tile, BK=32, 256 threads = 4 waves. M%64==0, N%64==0, K%32==0.
__global__ __launch_bounds__(256) void gemm3_bf16(
    const unsigned short* __restrict__ Ah, const unsigned short* __restrict__ Al,
    const unsigned short* __restrict__ Bh, const unsigned short* __restrict__ Bl,
    float* __restrict__ C, int M, int N, int K)
{
    __shared__ __align__(16) unsigned short Ahs[64 * LP];
    __shared__ __align__(16) unsigned short Als[64 * LP];
    __shared__ __align__(16) unsigned short Bhs[64 * LP];
    __shared__ __align__(16) unsigned short Bls[64 * LP];

    const int t = threadIdx.x;
    const int r  = t >> 2;
    const int kc = (t & 3) << 3;
    const int row0 = blockIdx.x * 64, col0 = blockIdx.y * 64;
    const int wave = t >> 6, lane = t & 63;
    const int m15 = lane & 15, q8 = (lane >> 4) << 3;

    const size_t aoff = (size_t)(row0 + r) * K + kc;
    const size_t boff = (size_t)(col0 + r) * K + kc;

    floatx4 acc[4] = { {0.f,0.f,0.f,0.f}, {0.f,0.f,0.f,0.f},
                       {0.f,0.f,0.f,0.f}, {0.f,0.f,0.f,0.f} };

    for (int k0 = 0; k0 < K; k0 += 32) {
        uint4 avh = *(const uint4*)(Ah + aoff + k0);
        uint4 avl = *(const uint4*)(Al + aoff + k0);
        uint4 bvh = *(const uint4*)(Bh + boff + k0);
        uint4 bvl = *(const uint4*)(Bl + boff + k0);
        *(uint4*)&Ahs[r * LP + kc] = avh;
        *(uint4*)&Als[r * LP + kc] = avl;
        *(uint4*)&Bhs[r * LP + kc] = bvh;
        *(uint4*)&Bls[r * LP + kc] = bvl;
        __syncthreads();

        short8 afh = *(const short8*)&Ahs[(wave * 16 + m15) * LP + q8];
        short8 afl = *(const short8*)&Als[(wave * 16 + m15) * LP + q8];
        #pragma unroll
        for (int j = 0; j < 4; ++j) {
            short8 bfh = *(const short8*)&Bhs[(j * 16 + m15) * LP + q8];
            short8 bfl = *(const short8*)&Bls[(j * 16 + m15) * LP + q8];
            acc[j] = __builtin_amdgcn_mfma_f32_16x16x32_bf16(afh, bfh, acc[j], 0, 0, 0);
            acc[j] = __builtin_amdgcn_mfma_f32_16x16x32_bf16(afh, bfl, acc[j], 0, 0, 0);
            acc[j] = __builtin_amdgcn_mfma_f32_16x16x32_bf16(afl, bfh, acc[j], 0, 0, 0);
        }
        __syncthreads();
    }

    // C/D layout: col = lane&15, row = (lane>>4)*4 + reg
    const int rbase = row0 + wave * 16 + (q8 >> 1);
    #pragma unroll
    for (int j = 0; j < 4; ++j) {
        int col = col0 + j * 16 + m15;
        #pragma unroll
        for (int rr = 0; rr < 4; ++rr)
            C[(size_t)(rbase + rr) * N + col] = acc[j][rr];
    }
}

// Single-precision bf16 MFMA GEMM (post-softmax path; 0.2 abs error is fine).
__global__ __launch_bounds__(256) void gemm_bf16(
    const unsigned short* __restrict__ A, const unsigned short* __restrict__ Bt,
    const float* __restrict__ bias, float* __restrict__ C,
    int M, int N, int K)
{
    __shared__ __align__(16) unsigned short As[64 * LP];
    __shared__ __align__(16) unsigned short Bs[64 * LP];

    const int t = threadIdx.x;
    const int r  = t >> 2;
    const int kc = (t & 3) << 3;
    const int row0 = blockIdx.x * 64, col0 = blockIdx.y * 64;
    const int wave = t >> 6, lane = t & 63;
    const int m15 = lane & 15, q8 = (lane >> 4) << 3;

    const unsigned short* Ap = A + (size_t)(row0 + r) * K + kc;
    const int bn = col0 + r;
    const unsigned short* Bp = Bt + (size_t)bn * K + kc;
    const bool bvalid = (bn < N);

    floatx4 acc[4] = { {0.f,0.f,0.f,0.f}, {0.f,0.f,0.f,0.f},
                       {0.f,0.f,0.f,0.f}, {0.f,0.f,0.f,0.f} };

    for (int k0 = 0; k0 < K; k0 += 32) {
        uint4 av = *(const uint4*)(Ap + k0);
        uint4 bv;
        if (bvalid) bv = *(const uint4*)(Bp + k0);
        else { bv.x = 0; bv.y = 0; bv.z = 0; bv.w = 0; }
        *(uint4*)&As[r * LP + kc] = av;
        *(uint4*)&Bs[r * LP + kc] = bv;
        __syncthreads();

        short8 af = *(const short8*)&As[(wave * 16 + m15) * LP + q8];
        #pragma unroll
        for (int j = 0; j < 4; ++j) {
            short8 bf = *(const short8*)&Bs[(j * 16 + m15) * LP + q8];
            acc[j] = __builtin_amdgcn_mfma_f32_16x16x32_bf16(af, bf, acc[j], 0, 0, 0);
        }
        __syncthreads();
    }

    const int rbase = row0 + wave * 16 + (q8 >> 1);
    #pragma unroll
    for (int j = 0; j < 4; ++j) {
        int col = col0 + j * 16 + m15;
        if (col < N) {
            float bvadd = bias ? bias[col] : 0.0f;
            #pragma unroll
            for (int rr = 0; rr < 4; ++rr)
                C[(size_t)(rbase + rr) * N + col] = acc[j][rr] + bvadd;
        }
    }
}

// Fused per-(b,p) additive attention; h1/h2 fp32 in, tanh(cont) bf16 out.
__global__ __launch_bounds__(256) void attn_fused(
    const float* __restrict__ h1,   // [2048][512]
    const float* __restrict__ h2,   // [8][64][512]
    const float* __restrict__ bias, // [512]
    const float* __restrict__ w3,   // [512]
    unsigned short* __restrict__ tcont) // [2048][2048] bf16
{
    __shared__ float h1s[ADIM];
    __shared__ float hbs[ADIM];
    __shared__ float w3s[ADIM];
    __shared__ float sc[64];

    const int bp = blockIdx.x;
    const int b  = bp >> 8;
    const int t  = threadIdx.x;
    const float* h1r = h1 + (size_t)bp * ADIM;
    const float* h2b = h2 + (size_t)b * 64 * ADIM;

    for (int i = t; i < ADIM; i += 256) {
        float v = h1r[i];
        h1s[i] = v;
        hbs[i] = v + bias[i];
        w3s[i] = w3[i];
    }
    __syncthreads();

    const int wave = t >> 6, lane = t & 63;
    #pragma unroll 4
    for (int qi = 0; qi < 16; ++qi) {
        int q = (wave << 4) + qi;
        const float* h2q = h2b + (q << 9);
        float s = 0.f;
        #pragma unroll
        for (int j = 0; j < 8; ++j) {
            int a = lane + (j << 6);
            s += tanh_fast(hbs[a] + h2q[a]) * w3s[a];
        }
        #pragma unroll
        for (int off = 32; off; off >>= 1) s += __shfl_down(s, off, 64);
        if (lane == 0) sc[q] = s;
    }
    __syncthreads();

    if (t < 64) {
        float e = sc[t];
        float m = e;
        #pragma unroll
        for (int off = 32; off; off >>= 1) m = fmaxf(m, __shfl_xor(m, off, 64));
        float ex = __expf(e - m);
        float s = ex;
        #pragma unroll
        for (int off = 32; off; off >>= 1) s += __shfl_xor(s, off, 64);
        sc[t] = ex / s;
    }
    __syncthreads();

    unsigned short* o = tcont + (size_t)bp * CDIM;
    for (int av = t; av < ADIM; av += 256) {
        float ta = 0.f;
        #pragma unroll 8
        for (int q = 0; q < 64; ++q) ta += sc[q] * h2b[(q << 9) + av];
        float hh = h1s[av];
        o[av]            = bf16r(tanh_fast(hh));
        o[ADIM + av]     = bf16r(tanh_fast(ta));
        o[2 * ADIM + av] = bf16r(tanh_fast(hh * ta));
        o[3 * ADIM + av] = bf16r(tanh_fast(hh - ta));
    }
}

extern "C" void kernel_launch(void* const* d_in, const int* in_sizes, int n_in,
                              void* d_out, int out_size, void* d_ws, size_t ws_size,
                              hipStream_t stream) {
    const float* video = (const float*)d_in[0];  // [8,256,1024]
    const float* text  = (const float*)d_in[1];  // [8,64,768]
    // masks (d_in[2], d_in[3]) are dead in the reference
    const float* w1   = (const float*)d_in[4];   // [1024,512]
    const float* w2   = (const float*)d_in[5];   // [768,512]
    const float* w3   = (const float*)d_in[6];   // [512,1]
    const float* bias = (const float*)d_in[7];   // [512]
    const float* w4   = (const float*)d_in[8];   // [2048,500]
    const float* b4   = (const float*)d_in[9];   // [500]
    float* out = (float*)d_out;                  // [8,256,500]

    char* ws = (char*)d_ws;
    size_t off = 0;
    unsigned short* vid_h = (unsigned short*)(ws + off); off += (size_t)MBP * VDIM * 2;
    unsigned short* vid_l = (unsigned short*)(ws + off); off += (size_t)MBP * VDIM * 2;
    unsigned short* txt_h = (unsigned short*)(ws + off); off += (size_t)MT * TDIM * 2;
    unsigned short* txt_l = (unsigned short*)(ws + off); off += (size_t)MT * TDIM * 2;
    unsigned short* w1t_h = (unsigned short*)(ws + off); off += (size_t)ADIM * VDIM * 2;
    unsigned short* w1t_l = (unsigned short*)(ws + off); off += (size_t)ADIM * VDIM * 2;
    unsigned short* w2t_h = (unsigned short*)(ws + off); off += (size_t)ADIM * TDIM * 2;
    unsigned short* w2t_l = (unsigned short*)(ws + off); off += (size_t)ADIM * TDIM * 2;
    unsigned short* w4t   = (unsigned short*)(ws + off); off += (size_t)NOUT * CDIM * 2;
    float*          h1    = (float*)(ws + off);          off += (size_t)MBP * ADIM * 4;
    float*          h2    = (float*)(ws + off);          off += (size_t)MT * ADIM * 4;
    unsigned short* tc    = (unsigned short*)(ws + off); off += (size_t)MBP * CDIM * 2;

    // conversions: activations split hi/lo; weights transposed split hi/lo
    conv_split<<<(MBP * VDIM / 4 + 255) / 256, 256, 0, stream>>>(video, vid_h, vid_l, MBP * VDIM / 4);
    conv_split<<<(MT * TDIM / 4 + 255) / 256, 256, 0, stream>>>(text, txt_h, txt_l, MT * TDIM / 4);
    transp_split<<<dim3(VDIM / 32, ADIM / 32), 256, 0, stream>>>(w1, w1t_h, w1t_l, VDIM, ADIM);
    transp_split<<<dim3(TDIM / 32, ADIM / 32), 256, 0, stream>>>(w2, w2t_h, w2t_l, TDIM, ADIM);
    transp_bf16<<<dim3(CDIM / 32, (NOUT + 31) / 32), 256, 0, stream>>>(w4, w4t, CDIM, NOUT);

    // h1 = video @ w1, h2 = text @ w2 — compensated (fp32-accurate, protects softmax)
    gemm3_bf16<<<dim3(MBP / 64, ADIM / 64), 256, 0, stream>>>(vid_h, vid_l, w1t_h, w1t_l, h1, MBP, ADIM, VDIM);
    gemm3_bf16<<<dim3(MT / 64, ADIM / 64), 256, 0, stream>>>(txt_h, txt_l, w2t_h, w2t_l, h2, MT, ADIM, TDIM);

    // fused attention -> tanh(cont) bf16
    attn_fused<<<MBP, 256, 0, stream>>>(h1, h2, bias, w3, tc);

    // out = tanh(cont) @ w4 + b4 — single bf16 (post-softmax, error ~0.2 ok)
    gemm_bf16<<<dim3(MBP / 64, (NOUT + 63) / 64), 256, 0, stream>>>(tc, w4t, b4, out, MBP, NOUT, CDIM);
}

// Round 5
// 182.361 us; speedup vs baseline: 2.4482x; 1.1396x over previous
//
#include <hip/hip_runtime.h>
#include <hip/hip_bf16.h>
#include <cstddef>

// Problem constants (B=8, S1=256, S2=64, VIDEO=1024, TEXT=768, ATTN=512, OUT=500)
#define MBP   2048   // B*S1
#define MT    512    // B*S2
#define ADIM  512
#define VDIM  1024
#define TDIM  768
#define NOUT  500
#define CDIM  2048   // 4*ADIM

typedef __attribute__((ext_vector_type(8))) short short8;    // 8 bf16 = 4 VGPRs
typedef __attribute__((ext_vector_type(4))) float floatx4;   // MFMA C/D frag

// tanh via native exp2 + rcp: rel err ~1e-6.
__device__ __forceinline__ float tanh_fast(float x) {
    float e = __builtin_amdgcn_exp2f(x * 2.88539008177793f);
    float r = __builtin_amdgcn_rcpf(e + 1.0f);
    return __builtin_fmaf(-2.0f, r, 1.0f);
}

__device__ __forceinline__ unsigned short bf16r(float x) {
    union { float f; unsigned int u; } c; c.f = x;
    unsigned int r = (c.u + 0x7fffu + ((c.u >> 16) & 1u)) >> 16;
    return (unsigned short)r;
}
__device__ __forceinline__ float bf2f(unsigned short h) {
    union { unsigned int u; float f; } c; c.u = ((unsigned int)h) << 16;
    return c.f;
}

// fp32 -> (hi, lo) bf16 split: x ~= hi + lo with residual ~2^-18 relative.
__global__ __launch_bounds__(256) void conv_split(
    const float* __restrict__ src,
    unsigned short* __restrict__ hi, unsigned short* __restrict__ lo, int n4)
{
    int i = blockIdx.x * 256 + threadIdx.x;
    if (i < n4) {
        float4 v = ((const float4*)src)[i];
        ushort4 h, l;
        h.x = bf16r(v.x); l.x = bf16r(v.x - bf2f(h.x));
        h.y = bf16r(v.y); l.y = bf16r(v.y - bf2f(h.y));
        h.z = bf16r(v.z); l.z = bf16r(v.z - bf2f(h.z));
        h.w = bf16r(v.w); l.w = bf16r(v.w - bf2f(h.w));
        ((ushort4*)hi)[i] = h;
        ((ushort4*)lo)[i] = l;
    }
}

// src [R][C] fp32 -> transpose [C][R], split hi/lo bf16. blockIdx.z batches.
__global__ __launch_bounds__(256) void transp_split(
    const float* __restrict__ src,
    unsigned short* __restrict__ hi, unsigned short* __restrict__ lo, int R, int C)
{
    __shared__ float tile[32][33];
    const float* s = src + (size_t)blockIdx.z * R * C;
    unsigned short* dh = hi + (size_t)blockIdx.z * R * C;
    unsigned short* dl = lo + (size_t)blockIdx.z * R * C;
    const int tx = threadIdx.x & 31, ty = threadIdx.x >> 5;
    const int r0 = blockIdx.x * 32, c0 = blockIdx.y * 32;
    #pragma unroll
    for (int i = 0; i < 4; ++i) {
        int r = r0 + ty + i * 8, c = c0 + tx;
        if (r < R && c < C) tile[ty + i * 8][tx] = s[(size_t)r * C + c];
    }
    __syncthreads();
    #pragma unroll
    for (int i = 0; i < 4; ++i) {
        int c = c0 + ty + i * 8, r = r0 + tx;
        if (c < C && r < R) {
            float v = tile[tx][ty + i * 8];
            unsigned short h = bf16r(v);
            dh[(size_t)c * R + r] = h;
            dl[(size_t)c * R + r] = bf16r(v - bf2f(h));
        }
    }
}

// src [R][C] fp32 -> dst [C][R] bf16 (single).
__global__ __launch_bounds__(256) void transp_bf16(
    const float* __restrict__ src, unsigned short* __restrict__ dst, int R, int C)
{
    __shared__ float tile[32][33];
    const int tx = threadIdx.x & 31, ty = threadIdx.x >> 5;
    const int r0 = blockIdx.x * 32, c0 = blockIdx.y * 32;
    #pragma unroll
    for (int i = 0; i < 4; ++i) {
        int r = r0 + ty + i * 8, c = c0 + tx;
        if (r < R && c < C) tile[ty + i * 8][tx] = src[(size_t)r * C + c];
    }
    __syncthreads();
    #pragma unroll
    for (int i = 0; i < 4; ++i) {
        int c = c0 + ty + i * 8, r = r0 + tx;
        if (c < C && r < R) dst[(size_t)c * R + r] = bf16r(tile[tx][ty + i * 8]);
    }
}

#define LP 40   // LDS row pitch in ushorts (80 B: 16-B aligned, odd bank stride)

// Compensated bf16 MFMA GEMM, pipelined: C = (Ah+Al) @ (Bh+Bl)^T fp32-accurate.
__global__ __launch_bounds__(256) void gemm3_bf16(
    const unsigned short* __restrict__ Ah, const unsigned short* __restrict__ Al,
    const unsigned short* __restrict__ Bh, const unsigned short* __restrict__ Bl,
    float* __restrict__ C, int M, int N, int K)
{
    __shared__ __align__(16) unsigned short Ahs[2][64 * LP];
    __shared__ __align__(16) unsigned short Als[2][64 * LP];
    __shared__ __align__(16) unsigned short Bhs[2][64 * LP];
    __shared__ __align__(16) unsigned short Bls[2][64 * LP];

    const int t = threadIdx.x;
    const int r  = t >> 2;
    const int kc = (t & 3) << 3;
    const int row0 = blockIdx.x * 64, col0 = blockIdx.y * 64;
    const int wave = t >> 6, lane = t & 63;
    const int m15 = lane & 15, q8 = (lane >> 4) << 3;

    const size_t aoff = (size_t)(row0 + r) * K + kc;
    const size_t boff = (size_t)(col0 + r) * K + kc;

    floatx4 acc[4] = { {0.f,0.f,0.f,0.f}, {0.f,0.f,0.f,0.f},
                       {0.f,0.f,0.f,0.f}, {0.f,0.f,0.f,0.f} };

    uint4 avh = *(const uint4*)(Ah + aoff);
    uint4 avl = *(const uint4*)(Al + aoff);
    uint4 bvh = *(const uint4*)(Bh + boff);
    uint4 bvl = *(const uint4*)(Bl + boff);
    *(uint4*)&Ahs[0][r * LP + kc] = avh;
    *(uint4*)&Als[0][r * LP + kc] = avl;
    *(uint4*)&Bhs[0][r * LP + kc] = bvh;
    *(uint4*)&Bls[0][r * LP + kc] = bvl;

    const int nIter = K >> 5;
    for (int i = 0; i < nIter; ++i) {
        __syncthreads();
        if (i + 1 < nIter) {
            int k0 = (i + 1) << 5;
            avh = *(const uint4*)(Ah + aoff + k0);
            avl = *(const uint4*)(Al + aoff + k0);
            bvh = *(const uint4*)(Bh + boff + k0);
            bvl = *(const uint4*)(Bl + boff + k0);
        }
        const int cur = i & 1;
        short8 afh = *(const short8*)&Ahs[cur][(wave * 16 + m15) * LP + q8];
        short8 afl = *(const short8*)&Als[cur][(wave * 16 + m15) * LP + q8];
        #pragma unroll
        for (int j = 0; j < 4; ++j) {
            short8 bfh = *(const short8*)&Bhs[cur][(j * 16 + m15) * LP + q8];
            short8 bfl = *(const short8*)&Bls[cur][(j * 16 + m15) * LP + q8];
            acc[j] = __builtin_amdgcn_mfma_f32_16x16x32_bf16(afh, bfh, acc[j], 0, 0, 0);
            acc[j] = __builtin_amdgcn_mfma_f32_16x16x32_bf16(afh, bfl, acc[j], 0, 0, 0);
            acc[j] = __builtin_amdgcn_mfma_f32_16x16x32_bf16(afl, bfh, acc[j], 0, 0, 0);
        }
        if (i + 1 < nIter) {
            const int nxt = cur ^ 1;
            *(uint4*)&Ahs[nxt][r * LP + kc] = avh;
            *(uint4*)&Als[nxt][r * LP + kc] = avl;
            *(uint4*)&Bhs[nxt][r * LP + kc] = bvh;
            *(uint4*)&Bls[nxt][r * LP + kc] = bvl;
        }
    }

    const int rbase = row0 + wave * 16 + (q8 >> 1);
    #pragma unroll
    for (int j = 0; j < 4; ++j) {
        int col = col0 + j * 16 + m15;
        #pragma unroll
        for (int rr = 0; rr < 4; ++rr)
            C[(size_t)(rbase + rr) * N + col] = acc[j][rr];
    }
}

// Single bf16 MFMA GEMM, pipelined (post-softmax path).
__global__ __launch_bounds__(256) void gemm_bf16(
    const unsigned short* __restrict__ A, const unsigned short* __restrict__ Bt,
    const float* __restrict__ bias, float* __restrict__ C,
    int M, int N, int K)
{
    __shared__ __align__(16) unsigned short As[2][64 * LP];
    __shared__ __align__(16) unsigned short Bs[2][64 * LP];

    const int t = threadIdx.x;
    const int r  = t >> 2;
    const int kc = (t & 3) << 3;
    const int row0 = blockIdx.x * 64, col0 = blockIdx.y * 64;
    const int wave = t >> 6, lane = t & 63;
    const int m15 = lane & 15, q8 = (lane >> 4) << 3;

    const unsigned short* Ap = A + (size_t)(row0 + r) * K + kc;
    const int bn = col0 + r;
    const unsigned short* Bp = Bt + (size_t)bn * K + kc;
    const bool bvalid = (bn < N);

    floatx4 acc[4] = { {0.f,0.f,0.f,0.f}, {0.f,0.f,0.f,0.f},
                       {0.f,0.f,0.f,0.f}, {0.f,0.f,0.f,0.f} };

    uint4 av = *(const uint4*)Ap;
    uint4 bv = {0u,0u,0u,0u};
    if (bvalid) bv = *(const uint4*)Bp;
    *(uint4*)&As[0][r * LP + kc] = av;
    *(uint4*)&Bs[0][r * LP + kc] = bv;

    const int nIter = K >> 5;
    for (int i = 0; i < nIter; ++i) {
        __syncthreads();
        if (i + 1 < nIter) {
            int k0 = (i + 1) << 5;
            av = *(const uint4*)(Ap + k0);
            if (bvalid) bv = *(const uint4*)(Bp + k0);
        }
        const int cur = i & 1;
        short8 af = *(const short8*)&As[cur][(wave * 16 + m15) * LP + q8];
        #pragma unroll
        for (int j = 0; j < 4; ++j) {
            short8 bf = *(const short8*)&Bs[cur][(j * 16 + m15) * LP + q8];
            acc[j] = __builtin_amdgcn_mfma_f32_16x16x32_bf16(af, bf, acc[j], 0, 0, 0);
        }
        if (i + 1 < nIter) {
            const int nxt = cur ^ 1;
            *(uint4*)&As[nxt][r * LP + kc] = av;
            *(uint4*)&Bs[nxt][r * LP + kc] = bv;
        }
    }

    const int rbase = row0 + wave * 16 + (q8 >> 1);
    #pragma unroll
    for (int j = 0; j < 4; ++j) {
        int col = col0 + j * 16 + m15;
        if (col < N) {
            float bvadd = bias ? bias[col] : 0.0f;
            #pragma unroll
            for (int rr = 0; rr < 4; ++rr)
                C[(size_t)(rbase + rr) * N + col] = acc[j][rr] + bvadd;
        }
    }
}

// Additive-attention logits + softmax; scores emitted as hi/lo bf16 split.
#define NP 4
#define TA 128
__global__ __launch_bounds__(256) void attn_scores(
    const float* __restrict__ h1,   // [2048][512]
    const float* __restrict__ h2,   // [8][64][512]
    const float* __restrict__ bias, // [512]
    const float* __restrict__ w3,   // [512]
    unsigned short* __restrict__ sc_h,  // [2048][64]
    unsigned short* __restrict__ sc_l)  // [2048][64]
{
    __shared__ __align__(16) float  h2t[TA / 4][64][4];  // 32 KB
    __shared__ __align__(16) float2 h1bw[NP][ADIM];      // 16 KB (h1+bias, w3)

    const int bp0 = blockIdx.x * NP;
    const int b   = bp0 >> 8;
    const int t   = threadIdx.x;
    const int wave = t >> 6, lane = t & 63;
    const float* h2b = h2 + (size_t)b * 64 * ADIM;

    for (int i = t; i < NP * ADIM; i += 256) {
        int p = i >> 9, a = i & 511;
        h1bw[p][a] = make_float2(h1[(size_t)(bp0 + p) * ADIM + a] + bias[a], w3[a]);
    }

    float acc = 0.f;
    for (int tile = 0; tile < ADIM / TA; ++tile) {
        const int a0 = tile * TA;
        __syncthreads();   // fences h1bw (tile 0) and prior readers
        #pragma unroll
        for (int i = 0; i < TA / (NP * 4); ++i) {
            int a4 = (wave * (TA / (NP * 4)) + i) * 4;
            float4 v = *(const float4*)(h2b + (size_t)lane * ADIM + a0 + a4);
            *(float4*)&h2t[a4 >> 2][lane][0] = v;
        }
        __syncthreads();
        const float2* bw = &h1bw[wave][a0];
        #pragma unroll 8
        for (int g = 0; g < TA / 4; ++g) {
            float4 hv = *(const float4*)&h2t[g][lane][0];
            float2 c0 = bw[g * 4 + 0], c1 = bw[g * 4 + 1];
            float2 c2 = bw[g * 4 + 2], c3 = bw[g * 4 + 3];
            acc = __builtin_fmaf(tanh_fast(c0.x + hv.x), c0.y, acc);
            acc = __builtin_fmaf(tanh_fast(c1.x + hv.y), c1.y, acc);
            acc = __builtin_fmaf(tanh_fast(c2.x + hv.z), c2.y, acc);
            acc = __builtin_fmaf(tanh_fast(c3.x + hv.w), c3.y, acc);
        }
    }

    // softmax across the wave (lane = q)
    float m = acc;
    #pragma unroll
    for (int off = 32; off; off >>= 1) m = fmaxf(m, __shfl_xor(m, off, 64));
    float ex = __builtin_amdgcn_exp2f((acc - m) * 1.44269504088896f);
    float s = ex;
    #pragma unroll
    for (int off = 32; off; off >>= 1) s += __shfl_xor(s, off, 64);
    float sc = ex * __builtin_amdgcn_rcpf(s);
    unsigned short h = bf16r(sc);
    size_t oidx = (size_t)(bp0 + wave) * 64 + lane;
    sc_h[oidx] = h;
    sc_l[oidx] = bf16r(sc - bf2f(h));
}

// text_attn = scores @ h2 via compensated MFMA (hi/lo on both operands,
// 3-term: ah*bh + ah*bl + al*bh), frags straight from L2, no LDS/barriers.
// + cont-feature epilogue -> tc bf16.
__global__ __launch_bounds__(256) void ta_cont(
    const unsigned short* __restrict__ sc_h,   // [2048][64]
    const unsigned short* __restrict__ sc_l,   // [2048][64]
    const unsigned short* __restrict__ h2t_h,  // [8][512][64]
    const unsigned short* __restrict__ h2t_l,  // [8][512][64]
    const float* __restrict__ h1,              // [2048][512] fp32
    unsigned short* __restrict__ tcont)        // [2048][2048] bf16
{
    const int row0 = blockIdx.x * 64;   // p-rows (same batch: 64 | 256)
    const int col0 = blockIdx.y * 64;   // a-cols
    const int b = row0 >> 8;
    const int t = threadIdx.x;
    const int wave = t >> 6, lane = t & 63;
    const int m15 = lane & 15, q8 = (lane >> 4) << 3;

    const size_t aidx = (size_t)(row0 + wave * 16 + m15) * 64 + q8;
    short8 af0h = *(const short8*)&sc_h[aidx];
    short8 af1h = *(const short8*)&sc_h[aidx + 32];
    short8 af0l = *(const short8*)&sc_l[aidx];
    short8 af1l = *(const short8*)&sc_l[aidx + 32];
    const size_t bbase = (size_t)b * ADIM * 64;

    floatx4 acc[4];
    #pragma unroll
    for (int j = 0; j < 4; ++j) {
        size_t boff = bbase + (size_t)(col0 + j * 16 + m15) * 64 + q8;
        short8 bf0h = *(const short8*)&h2t_h[boff];
        short8 bf1h = *(const short8*)&h2t_h[boff + 32];
        short8 bf0l = *(const short8*)&h2t_l[boff];
        short8 bf1l = *(const short8*)&h2t_l[boff + 32];
        floatx4 z = {0.f, 0.f, 0.f, 0.f};
        z = __builtin_amdgcn_mfma_f32_16x16x32_bf16(af0h, bf0h, z, 0, 0, 0);
        z = __builtin_amdgcn_mfma_f32_16x16x32_bf16(af0h, bf0l, z, 0, 0, 0);
        z = __builtin_amdgcn_mfma_f32_16x16x32_bf16(af0l, bf0h, z, 0, 0, 0);
        z = __builtin_amdgcn_mfma_f32_16x16x32_bf16(af1h, bf1h, z, 0, 0, 0);
        z = __builtin_amdgcn_mfma_f32_16x16x32_bf16(af1h, bf1l, z, 0, 0, 0);
        acc[j] = __builtin_amdgcn_mfma_f32_16x16x32_bf16(af1l, bf1h, z, 0, 0, 0);
    }

    const int rbase = row0 + wave * 16 + (q8 >> 1);
    #pragma unroll
    for (int j = 0; j < 4; ++j) {
        int a = col0 + j * 16 + m15;
        #pragma unroll
        for (int rr = 0; rr < 4; ++rr) {
            int row = rbase + rr;
            float ta = acc[j][rr];
            float hh = h1[(size_t)row * ADIM + a];
            unsigned short* o = tcont + (size_t)row * CDIM;
            o[a]            = bf16r(tanh_fast(hh));
            o[ADIM + a]     = bf16r(tanh_fast(ta));
            o[2 * ADIM + a] = bf16r(tanh_fast(hh * ta));
            o[3 * ADIM + a] = bf16r(tanh_fast(hh - ta));
        }
    }
}

extern "C" void kernel_launch(void* const* d_in, const int* in_sizes, int n_in,
                              void* d_out, int out_size, void* d_ws, size_t ws_size,
                              hipStream_t stream) {
    const float* video = (const float*)d_in[0];  // [8,256,1024]
    const float* text  = (const float*)d_in[1];  // [8,64,768]
    // masks (d_in[2], d_in[3]) are dead in the reference
    const float* w1   = (const float*)d_in[4];   // [1024,512]
    const float* w2   = (const float*)d_in[5];   // [768,512]
    const float* w3   = (const float*)d_in[6];   // [512,1]
    const float* bias = (const float*)d_in[7];   // [512]
    const float* w4   = (const float*)d_in[8];   // [2048,500]
    const float* b4   = (const float*)d_in[9];   // [500]
    float* out = (float*)d_out;                  // [8,256,500]

    char* ws = (char*)d_ws;
    size_t off = 0;
    unsigned short* vid_h = (unsigned short*)(ws + off); off += (size_t)MBP * VDIM * 2;
    unsigned short* vid_l = (unsigned short*)(ws + off); off += (size_t)MBP * VDIM * 2;
    unsigned short* txt_h = (unsigned short*)(ws + off); off += (size_t)MT * TDIM * 2;
    unsigned short* txt_l = (unsigned short*)(ws + off); off += (size_t)MT * TDIM * 2;
    unsigned short* w1t_h = (unsigned short*)(ws + off); off += (size_t)ADIM * VDIM * 2;
    unsigned short* w1t_l = (unsigned short*)(ws + off); off += (size_t)ADIM * VDIM * 2;
    unsigned short* w2t_h = (unsigned short*)(ws + off); off += (size_t)ADIM * TDIM * 2;
    unsigned short* w2t_l = (unsigned short*)(ws + off); off += (size_t)ADIM * TDIM * 2;
    unsigned short* w4t   = (unsigned short*)(ws + off); off += (size_t)NOUT * CDIM * 2;
    float*          h1    = (float*)(ws + off);          off += (size_t)MBP * ADIM * 4;
    float*          h2    = (float*)(ws + off);          off += (size_t)MT * ADIM * 4;
    unsigned short* sc_h  = (unsigned short*)(ws + off); off += (size_t)MBP * 64 * 2;
    unsigned short* sc_l  = (unsigned short*)(ws + off); off += (size_t)MBP * 64 * 2;
    unsigned short* h2t_h = (unsigned short*)(ws + off); off += (size_t)8 * ADIM * 64 * 2;
    unsigned short* h2t_l = (unsigned short*)(ws + off); off += (size_t)8 * ADIM * 64 * 2;
    unsigned short* tc    = (unsigned short*)(ws + off); off += (size_t)MBP * CDIM * 2;

    // conversions
    conv_split<<<(MBP * VDIM / 4 + 255) / 256, 256, 0, stream>>>(video, vid_h, vid_l, MBP * VDIM / 4);
    conv_split<<<(MT * TDIM / 4 + 255) / 256, 256, 0, stream>>>(text, txt_h, txt_l, MT * TDIM / 4);
    transp_split<<<dim3(VDIM / 32, ADIM / 32, 1), 256, 0, stream>>>(w1, w1t_h, w1t_l, VDIM, ADIM);
    transp_split<<<dim3(TDIM / 32, ADIM / 32, 1), 256, 0, stream>>>(w2, w2t_h, w2t_l, TDIM, ADIM);
    transp_bf16<<<dim3(CDIM / 32, (NOUT + 31) / 32), 256, 0, stream>>>(w4, w4t, CDIM, NOUT);

    // h1 = video @ w1, h2 = text @ w2 — compensated (fp32-accurate logits)
    gemm3_bf16<<<dim3(MBP / 64, ADIM / 64), 256, 0, stream>>>(vid_h, vid_l, w1t_h, w1t_l, h1, MBP, ADIM, VDIM);
    gemm3_bf16<<<dim3(MT / 64, ADIM / 64), 256, 0, stream>>>(txt_h, txt_l, w2t_h, w2t_l, h2, MT, ADIM, TDIM);

    // h2 -> per-batch transposed split bf16 [8][512][64] for the ta MFMA
    transp_split<<<dim3(64 / 32, ADIM / 32, 8), 256, 0, stream>>>(h2, h2t_h, h2t_l, 64, ADIM);

    // logits + softmax -> scores (hi/lo bf16)
    attn_scores<<<MBP / NP, 256, 0, stream>>>(h1, h2, bias, w3, sc_h, sc_l);

    // text_attn via compensated MFMA + cont features -> tc bf16
    ta_cont<<<dim3(MBP / 64, ADIM / 64), 256, 0, stream>>>(sc_h, sc_l, h2t_h, h2t_l, h1, tc);

    // out = tanh(cont) @ w4 + b4
    gemm_bf16<<<dim3(MBP / 64, (NOUT + 63) / 64), 256, 0, stream>>>(tc, w4t, b4, out, MBP, NOUT, CDIM);
}

// Round 6
// 165.098 us; speedup vs baseline: 2.7042x; 1.1046x over previous
//
#include <hip/hip_runtime.h>
#include <hip/hip_bf16.h>
#include <cstddef>

// Problem constants (B=8, S1=256, S2=64, VIDEO=1024, TEXT=768, ATTN=512, OUT=500)
#define MBP   2048   // B*S1
#define MT    512    // B*S2
#define ADIM  512
#define VDIM  1024
#define TDIM  768
#define NOUT  500
#define CDIM  2048   // 4*ADIM

typedef __attribute__((ext_vector_type(8))) short short8;    // 8 bf16 = 4 VGPRs
typedef __attribute__((ext_vector_type(4))) float floatx4;   // MFMA C/D frag

// tanh via native exp2 + rcp: rel err ~1e-6.
__device__ __forceinline__ float tanh_fast(float x) {
    float e = __builtin_amdgcn_exp2f(x * 2.88539008177793f);
    float r = __builtin_amdgcn_rcpf(e + 1.0f);
    return __builtin_fmaf(-2.0f, r, 1.0f);
}

__device__ __forceinline__ unsigned short bf16r(float x) {
    union { float f; unsigned int u; } c; c.f = x;
    unsigned int r = (c.u + 0x7fffu + ((c.u >> 16) & 1u)) >> 16;
    return (unsigned short)r;
}
__device__ __forceinline__ float bf2f(unsigned short h) {
    union { unsigned int u; float f; } c; c.u = ((unsigned int)h) << 16;
    return c.f;
}

// ---------- fused prep: all conversions/transposes in ONE dispatch ----------
__device__ __forceinline__ void conv_split_body(
    const float* __restrict__ src, unsigned short* __restrict__ hi,
    unsigned short* __restrict__ lo, int blk)
{
    int i = blk * 256 + threadIdx.x;
    float4 v = ((const float4*)src)[i];
    ushort4 h, l;
    h.x = bf16r(v.x); l.x = bf16r(v.x - bf2f(h.x));
    h.y = bf16r(v.y); l.y = bf16r(v.y - bf2f(h.y));
    h.z = bf16r(v.z); l.z = bf16r(v.z - bf2f(h.z));
    h.w = bf16r(v.w); l.w = bf16r(v.w - bf2f(h.w));
    ((ushort4*)hi)[i] = h;
    ((ushort4*)lo)[i] = l;
}

__device__ __forceinline__ void transp_split_body(
    float (*tile)[33], const float* __restrict__ src,
    unsigned short* __restrict__ hi, unsigned short* __restrict__ lo,
    int R, int C, int bx, int by)
{
    const int tx = threadIdx.x & 31, ty = threadIdx.x >> 5;
    const int r0 = bx * 32, c0 = by * 32;
    #pragma unroll
    for (int i = 0; i < 4; ++i) {
        int r = r0 + ty + i * 8, c = c0 + tx;
        if (r < R && c < C) tile[ty + i * 8][tx] = src[(size_t)r * C + c];
    }
    __syncthreads();
    #pragma unroll
    for (int i = 0; i < 4; ++i) {
        int c = c0 + ty + i * 8, r = r0 + tx;
        if (c < C && r < R) {
            float v = tile[tx][ty + i * 8];
            unsigned short h = bf16r(v);
            hi[(size_t)c * R + r] = h;
            lo[(size_t)c * R + r] = bf16r(v - bf2f(h));
        }
    }
}

__device__ __forceinline__ void transp_single_body(
    float (*tile)[33], const float* __restrict__ src,
    unsigned short* __restrict__ dst, int R, int C, int bx, int by)
{
    const int tx = threadIdx.x & 31, ty = threadIdx.x >> 5;
    const int r0 = bx * 32, c0 = by * 32;
    #pragma unroll
    for (int i = 0; i < 4; ++i) {
        int r = r0 + ty + i * 8, c = c0 + tx;
        if (r < R && c < C) tile[ty + i * 8][tx] = src[(size_t)r * C + c];
    }
    __syncthreads();
    #pragma unroll
    for (int i = 0; i < 4; ++i) {
        int c = c0 + ty + i * 8, r = r0 + tx;
        if (c < C && r < R) dst[(size_t)c * R + r] = bf16r(tile[tx][ty + i * 8]);
    }
}

// block ranges: [0,2048) video conv; [2048,2432) text conv; [2432,2944) w1;
// [2944,3328) w2; [3328,4352) w4. (524288/256=2048, 98304/256=384 exact.)
__global__ __launch_bounds__(256) void prep(
    const float* __restrict__ video, const float* __restrict__ text,
    const float* __restrict__ w1, const float* __restrict__ w2,
    const float* __restrict__ w4,
    unsigned short* __restrict__ vid_h, unsigned short* __restrict__ vid_l,
    unsigned short* __restrict__ txt_h, unsigned short* __restrict__ txt_l,
    unsigned short* __restrict__ w1t_h, unsigned short* __restrict__ w1t_l,
    unsigned short* __restrict__ w2t_h, unsigned short* __restrict__ w2t_l,
    unsigned short* __restrict__ w4t)
{
    __shared__ float tile[32][33];
    const int bid = blockIdx.x;
    if (bid < 2048) {
        conv_split_body(video, vid_h, vid_l, bid);
    } else if (bid < 2432) {
        conv_split_body(text, txt_h, txt_l, bid - 2048);
    } else if (bid < 2944) {
        int idx = bid - 2432;
        transp_split_body(tile, w1, w1t_h, w1t_l, VDIM, ADIM, idx & 31, idx >> 5);
    } else if (bid < 3328) {
        int idx = bid - 2944;
        transp_split_body(tile, w2, w2t_h, w2t_l, TDIM, ADIM, idx % 24, idx / 24);
    } else {
        int idx = bid - 3328;
        transp_single_body(tile, w4, w4t, CDIM, NOUT, idx & 63, idx >> 6);
    }
}

#define LP 40   // LDS row pitch in ushorts (80 B: 16-B aligned, odd bank stride)

// Compensated bf16 MFMA GEMM, pipelined; h1 (blocks 0..31) and h2 (32..39)
// in ONE dispatch. h2 path also emits transposed split h2t from the fp32 acc.
__global__ __launch_bounds__(256) void gemm3_both(
    const unsigned short* __restrict__ vid_h, const unsigned short* __restrict__ vid_l,
    const unsigned short* __restrict__ w1t_h, const unsigned short* __restrict__ w1t_l,
    const unsigned short* __restrict__ txt_h, const unsigned short* __restrict__ txt_l,
    const unsigned short* __restrict__ w2t_h, const unsigned short* __restrict__ w2t_l,
    float* __restrict__ h1, float* __restrict__ h2,
    unsigned short* __restrict__ h2t_h, unsigned short* __restrict__ h2t_l)
{
    __shared__ __align__(16) unsigned short Ahs[2][64 * LP];
    __shared__ __align__(16) unsigned short Als[2][64 * LP];
    __shared__ __align__(16) unsigned short Bhs[2][64 * LP];
    __shared__ __align__(16) unsigned short Bls[2][64 * LP];

    const bool isH2 = (blockIdx.x >= 32);
    const unsigned short *Ah, *Al, *Bh, *Bl;
    float* C;
    int K, row0;
    if (!isH2) { Ah = vid_h; Al = vid_l; Bh = w1t_h; Bl = w1t_l; C = h1; K = VDIM; row0 = blockIdx.x * 64; }
    else       { Ah = txt_h; Al = txt_l; Bh = w2t_h; Bl = w2t_l; C = h2; K = TDIM; row0 = (blockIdx.x - 32) * 64; }

    const int t = threadIdx.x;
    const int r  = t >> 2;
    const int kc = (t & 3) << 3;
    const int col0 = blockIdx.y * 64;
    const int wave = t >> 6, lane = t & 63;
    const int m15 = lane & 15, q8 = (lane >> 4) << 3;

    const size_t aoff = (size_t)(row0 + r) * K + kc;
    const size_t boff = (size_t)(col0 + r) * K + kc;

    floatx4 acc[4] = { {0.f,0.f,0.f,0.f}, {0.f,0.f,0.f,0.f},
                       {0.f,0.f,0.f,0.f}, {0.f,0.f,0.f,0.f} };

    uint4 avh = *(const uint4*)(Ah + aoff);
    uint4 avl = *(const uint4*)(Al + aoff);
    uint4 bvh = *(const uint4*)(Bh + boff);
    uint4 bvl = *(const uint4*)(Bl + boff);
    *(uint4*)&Ahs[0][r * LP + kc] = avh;
    *(uint4*)&Als[0][r * LP + kc] = avl;
    *(uint4*)&Bhs[0][r * LP + kc] = bvh;
    *(uint4*)&Bls[0][r * LP + kc] = bvl;

    const int nIter = K >> 5;
    for (int i = 0; i < nIter; ++i) {
        __syncthreads();
        if (i + 1 < nIter) {
            int k0 = (i + 1) << 5;
            avh = *(const uint4*)(Ah + aoff + k0);
            avl = *(const uint4*)(Al + aoff + k0);
            bvh = *(const uint4*)(Bh + boff + k0);
            bvl = *(const uint4*)(Bl + boff + k0);
        }
        const int cur = i & 1;
        short8 afh = *(const short8*)&Ahs[cur][(wave * 16 + m15) * LP + q8];
        short8 afl = *(const short8*)&Als[cur][(wave * 16 + m15) * LP + q8];
        #pragma unroll
        for (int j = 0; j < 4; ++j) {
            short8 bfh = *(const short8*)&Bhs[cur][(j * 16 + m15) * LP + q8];
            short8 bfl = *(const short8*)&Bls[cur][(j * 16 + m15) * LP + q8];
            acc[j] = __builtin_amdgcn_mfma_f32_16x16x32_bf16(afh, bfh, acc[j], 0, 0, 0);
            acc[j] = __builtin_amdgcn_mfma_f32_16x16x32_bf16(afh, bfl, acc[j], 0, 0, 0);
            acc[j] = __builtin_amdgcn_mfma_f32_16x16x32_bf16(afl, bfh, acc[j], 0, 0, 0);
        }
        if (i + 1 < nIter) {
            const int nxt = cur ^ 1;
            *(uint4*)&Ahs[nxt][r * LP + kc] = avh;
            *(uint4*)&Als[nxt][r * LP + kc] = avl;
            *(uint4*)&Bhs[nxt][r * LP + kc] = bvh;
            *(uint4*)&Bls[nxt][r * LP + kc] = bvl;
        }
    }

    // C/D layout: col = lane&15, row = (lane>>4)*4 + reg
    const int rbase = row0 + wave * 16 + (q8 >> 1);
    #pragma unroll
    for (int j = 0; j < 4; ++j) {
        int col = col0 + j * 16 + m15;
        #pragma unroll
        for (int rr = 0; rr < 4; ++rr) {
            int row = rbase + rr;
            float v = acc[j][rr];
            C[(size_t)row * ADIM + col] = v;
            if (isH2) {
                // h2t[b][a][q], b=row>>6, q=row&63, a=col
                size_t idx = (size_t)(row >> 6) * (ADIM * 64) + (size_t)col * 64 + (row & 63);
                unsigned short h = bf16r(v);
                h2t_h[idx] = h;
                h2t_l[idx] = bf16r(v - bf2f(h));
            }
        }
    }
}

// Single bf16 MFMA GEMM, pipelined (post-softmax final GEMM).
__global__ __launch_bounds__(256) void gemm_bf16(
    const unsigned short* __restrict__ A, const unsigned short* __restrict__ Bt,
    const float* __restrict__ bias, float* __restrict__ C,
    int M, int N, int K)
{
    __shared__ __align__(16) unsigned short As[2][64 * LP];
    __shared__ __align__(16) unsigned short Bs[2][64 * LP];

    const int t = threadIdx.x;
    const int r  = t >> 2;
    const int kc = (t & 3) << 3;
    const int row0 = blockIdx.x * 64, col0 = blockIdx.y * 64;
    const int wave = t >> 6, lane = t & 63;
    const int m15 = lane & 15, q8 = (lane >> 4) << 3;

    const unsigned short* Ap = A + (size_t)(row0 + r) * K + kc;
    const int bn = col0 + r;
    const unsigned short* Bp = Bt + (size_t)bn * K + kc;
    const bool bvalid = (bn < N);

    floatx4 acc[4] = { {0.f,0.f,0.f,0.f}, {0.f,0.f,0.f,0.f},
                       {0.f,0.f,0.f,0.f}, {0.f,0.f,0.f,0.f} };

    uint4 av = *(const uint4*)Ap;
    uint4 bv = {0u,0u,0u,0u};
    if (bvalid) bv = *(const uint4*)Bp;
    *(uint4*)&As[0][r * LP + kc] = av;
    *(uint4*)&Bs[0][r * LP + kc] = bv;

    const int nIter = K >> 5;
    for (int i = 0; i < nIter; ++i) {
        __syncthreads();
        if (i + 1 < nIter) {
            int k0 = (i + 1) << 5;
            av = *(const uint4*)(Ap + k0);
            if (bvalid) bv = *(const uint4*)(Bp + k0);
        }
        const int cur = i & 1;
        short8 af = *(const short8*)&As[cur][(wave * 16 + m15) * LP + q8];
        #pragma unroll
        for (int j = 0; j < 4; ++j) {
            short8 bf = *(const short8*)&Bs[cur][(j * 16 + m15) * LP + q8];
            acc[j] = __builtin_amdgcn_mfma_f32_16x16x32_bf16(af, bf, acc[j], 0, 0, 0);
        }
        if (i + 1 < nIter) {
            const int nxt = cur ^ 1;
            *(uint4*)&As[nxt][r * LP + kc] = av;
            *(uint4*)&Bs[nxt][r * LP + kc] = bv;
        }
    }

    const int rbase = row0 + wave * 16 + (q8 >> 1);
    #pragma unroll
    for (int j = 0; j < 4; ++j) {
        int col = col0 + j * 16 + m15;
        if (col < N) {
            float bvadd = bias ? bias[col] : 0.0f;
            #pragma unroll
            for (int rr = 0; rr < 4; ++rr)
                C[(size_t)(rbase + rr) * N + col] = acc[j][rr] + bvadd;
        }
    }
}

// Additive-attention logits + softmax; scores emitted as hi/lo bf16 split.
#define NP 4
#define TA 128
__global__ __launch_bounds__(256) void attn_scores(
    const float* __restrict__ h1,   // [2048][512]
    const float* __restrict__ h2,   // [8][64][512]
    const float* __restrict__ bias, // [512]
    const float* __restrict__ w3,   // [512]
    unsigned short* __restrict__ sc_h,  // [2048][64]
    unsigned short* __restrict__ sc_l)  // [2048][64]
{
    __shared__ __align__(16) float  h2t[TA / 4][64][4];  // 32 KB
    __shared__ __align__(16) float2 h1bw[NP][ADIM];      // 16 KB (h1+bias, w3)

    const int bp0 = blockIdx.x * NP;
    const int b   = bp0 >> 8;
    const int t   = threadIdx.x;
    const int wave = t >> 6, lane = t & 63;
    const float* h2b = h2 + (size_t)b * 64 * ADIM;

    for (int i = t; i < NP * ADIM; i += 256) {
        int p = i >> 9, a = i & 511;
        h1bw[p][a] = make_float2(h1[(size_t)(bp0 + p) * ADIM + a] + bias[a], w3[a]);
    }

    float acc = 0.f;
    for (int tile = 0; tile < ADIM / TA; ++tile) {
        const int a0 = tile * TA;
        __syncthreads();   // fences h1bw (tile 0) and prior readers
        #pragma unroll
        for (int i = 0; i < TA / (NP * 4); ++i) {
            int a4 = (wave * (TA / (NP * 4)) + i) * 4;
            float4 v = *(const float4*)(h2b + (size_t)lane * ADIM + a0 + a4);
            *(float4*)&h2t[a4 >> 2][lane][0] = v;
        }
        __syncthreads();
        const float2* bw = &h1bw[wave][a0];
        #pragma unroll 8
        for (int g = 0; g < TA / 4; ++g) {
            float4 hv = *(const float4*)&h2t[g][lane][0];
            float2 c0 = bw[g * 4 + 0], c1 = bw[g * 4 + 1];
            float2 c2 = bw[g * 4 + 2], c3 = bw[g * 4 + 3];
            acc = __builtin_fmaf(tanh_fast(c0.x + hv.x), c0.y, acc);
            acc = __builtin_fmaf(tanh_fast(c1.x + hv.y), c1.y, acc);
            acc = __builtin_fmaf(tanh_fast(c2.x + hv.z), c2.y, acc);
            acc = __builtin_fmaf(tanh_fast(c3.x + hv.w), c3.y, acc);
        }
    }

    // softmax across the wave (lane = q)
    float m = acc;
    #pragma unroll
    for (int off = 32; off; off >>= 1) m = fmaxf(m, __shfl_xor(m, off, 64));
    float ex = __builtin_amdgcn_exp2f((acc - m) * 1.44269504088896f);
    float s = ex;
    #pragma unroll
    for (int off = 32; off; off >>= 1) s += __shfl_xor(s, off, 64);
    float sc = ex * __builtin_amdgcn_rcpf(s);
    unsigned short h = bf16r(sc);
    size_t oidx = (size_t)(bp0 + wave) * 64 + lane;
    sc_h[oidx] = h;
    sc_l[oidx] = bf16r(sc - bf2f(h));
}

// text_attn = scores @ h2 via compensated MFMA + cont features -> tc bf16.
__global__ __launch_bounds__(256) void ta_cont(
    const unsigned short* __restrict__ sc_h,   // [2048][64]
    const unsigned short* __restrict__ sc_l,   // [2048][64]
    const unsigned short* __restrict__ h2t_h,  // [8][512][64]
    const unsigned short* __restrict__ h2t_l,  // [8][512][64]
    const float* __restrict__ h1,              // [2048][512] fp32
    unsigned short* __restrict__ tcont)        // [2048][2048] bf16
{
    const int row0 = blockIdx.x * 64;   // p-rows (same batch: 64 | 256)
    const int col0 = blockIdx.y * 64;   // a-cols
    const int b = row0 >> 8;
    const int t = threadIdx.x;
    const int wave = t >> 6, lane = t & 63;
    const int m15 = lane & 15, q8 = (lane >> 4) << 3;

    const size_t aidx = (size_t)(row0 + wave * 16 + m15) * 64 + q8;
    short8 af0h = *(const short8*)&sc_h[aidx];
    short8 af1h = *(const short8*)&sc_h[aidx + 32];
    short8 af0l = *(const short8*)&sc_l[aidx];
    short8 af1l = *(const short8*)&sc_l[aidx + 32];
    const size_t bbase = (size_t)b * ADIM * 64;

    floatx4 acc[4];
    #pragma unroll
    for (int j = 0; j < 4; ++j) {
        size_t boff = bbase + (size_t)(col0 + j * 16 + m15) * 64 + q8;
        short8 bf0h = *(const short8*)&h2t_h[boff];
        short8 bf1h = *(const short8*)&h2t_h[boff + 32];
        short8 bf0l = *(const short8*)&h2t_l[boff];
        short8 bf1l = *(const short8*)&h2t_l[boff + 32];
        floatx4 z = {0.f, 0.f, 0.f, 0.f};
        z = __builtin_amdgcn_mfma_f32_16x16x32_bf16(af0h, bf0h, z, 0, 0, 0);
        z = __builtin_amdgcn_mfma_f32_16x16x32_bf16(af0h, bf0l, z, 0, 0, 0);
        z = __builtin_amdgcn_mfma_f32_16x16x32_bf16(af0l, bf0h, z, 0, 0, 0);
        z = __builtin_amdgcn_mfma_f32_16x16x32_bf16(af1h, bf1h, z, 0, 0, 0);
        z = __builtin_amdgcn_mfma_f32_16x16x32_bf16(af1h, bf1l, z, 0, 0, 0);
        acc[j] = __builtin_amdgcn_mfma_f32_16x16x32_bf16(af1l, bf1h, z, 0, 0, 0);
    }

    const int rbase = row0 + wave * 16 + (q8 >> 1);
    #pragma unroll
    for (int j = 0; j < 4; ++j) {
        int a = col0 + j * 16 + m15;
        #pragma unroll
        for (int rr = 0; rr < 4; ++rr) {
            int row = rbase + rr;
            float ta = acc[j][rr];
            float hh = h1[(size_t)row * ADIM + a];
            unsigned short* o = tcont + (size_t)row * CDIM;
            o[a]            = bf16r(tanh_fast(hh));
            o[ADIM + a]     = bf16r(tanh_fast(ta));
            o[2 * ADIM + a] = bf16r(tanh_fast(hh * ta));
            o[3 * ADIM + a] = bf16r(tanh_fast(hh - ta));
        }
    }
}

extern "C" void kernel_launch(void* const* d_in, const int* in_sizes, int n_in,
                              void* d_out, int out_size, void* d_ws, size_t ws_size,
                              hipStream_t stream) {
    const float* video = (const float*)d_in[0];  // [8,256,1024]
    const float* text  = (const float*)d_in[1];  // [8,64,768]
    // masks (d_in[2], d_in[3]) are dead in the reference
    const float* w1   = (const float*)d_in[4];   // [1024,512]
    const float* w2   = (const float*)d_in[5];   // [768,512]
    const float* w3   = (const float*)d_in[6];   // [512,1]
    const float* bias = (const float*)d_in[7];   // [512]
    const float* w4   = (const float*)d_in[8];   // [2048,500]
    const float* b4   = (const float*)d_in[9];   // [500]
    float* out = (float*)d_out;                  // [8,256,500]

    char* ws = (char*)d_ws;
    size_t off = 0;
    unsigned short* vid_h = (unsigned short*)(ws + off); off += (size_t)MBP * VDIM * 2;
    unsigned short* vid_l = (unsigned short*)(ws + off); off += (size_t)MBP * VDIM * 2;
    unsigned short* txt_h = (unsigned short*)(ws + off); off += (size_t)MT * TDIM * 2;
    unsigned short* txt_l = (unsigned short*)(ws + off); off += (size_t)MT * TDIM * 2;
    unsigned short* w1t_h = (unsigned short*)(ws + off); off += (size_t)ADIM * VDIM * 2;
    unsigned short* w1t_l = (unsigned short*)(ws + off); off += (size_t)ADIM * VDIM * 2;
    unsigned short* w2t_h = (unsigned short*)(ws + off); off += (size_t)ADIM * TDIM * 2;
    unsigned short* w2t_l = (unsigned short*)(ws + off); off += (size_t)ADIM * TDIM * 2;
    unsigned short* w4t   = (unsigned short*)(ws + off); off += (size_t)NOUT * CDIM * 2;
    float*          h1    = (float*)(ws + off);          off += (size_t)MBP * ADIM * 4;
    float*          h2    = (float*)(ws + off);          off += (size_t)MT * ADIM * 4;
    unsigned short* sc_h  = (unsigned short*)(ws + off); off += (size_t)MBP * 64 * 2;
    unsigned short* sc_l  = (unsigned short*)(ws + off); off += (size_t)MBP * 64 * 2;
    unsigned short* h2t_h = (unsigned short*)(ws + off); off += (size_t)8 * ADIM * 64 * 2;
    unsigned short* h2t_l = (unsigned short*)(ws + off); off += (size_t)8 * ADIM * 64 * 2;
    unsigned short* tc    = (unsigned short*)(ws + off); off += (size_t)MBP * CDIM * 2;

    // 1) all conversions/transposes (one dispatch)
    prep<<<4352, 256, 0, stream>>>(video, text, w1, w2, w4,
                                   vid_h, vid_l, txt_h, txt_l,
                                   w1t_h, w1t_l, w2t_h, w2t_l, w4t);

    // 2) h1 & h2 compensated GEMMs (one dispatch); h2 path also emits h2t split
    gemm3_both<<<dim3(40, 8), 256, 0, stream>>>(vid_h, vid_l, w1t_h, w1t_l,
                                                txt_h, txt_l, w2t_h, w2t_l,
                                                h1, h2, h2t_h, h2t_l);

    // 3) logits + softmax -> scores (hi/lo bf16)
    attn_scores<<<MBP / NP, 256, 0, stream>>>(h1, h2, bias, w3, sc_h, sc_l);

    // 4) text_attn via compensated MFMA + cont features -> tc bf16
    ta_cont<<<dim3(MBP / 64, ADIM / 64), 256, 0, stream>>>(sc_h, sc_l, h2t_h, h2t_l, h1, tc);

    // 5) out = tanh(cont) @ w4 + b4
    gemm_bf16<<<dim3(MBP / 64, (NOUT + 63) / 64), 256, 0, stream>>>(tc, w4t, b4, out, MBP, NOUT, CDIM);
}